// Round 10
// baseline (2878.122 us; speedup 1.0000x reference)
//
#include <hip/hip_runtime.h>
#include <stdint.h>

// Borůvka maximum-spanning-forest == Kruskal acceptance set under the strict
// total order (score desc, edge-index asc). Multi-launch (kernel boundary =
// cheap barrier; coop grid.sync measured 2.3x slower, R2). Two kernels per
// round: scan (bid) and choose (winner mark + hook + next-buffer reset).
//
// Structure (R10 = R9 + compile fix): no compaction (records die too slowly
// on random graphs — R5); records updated IN PLACE (dead => a==b). Scan: 4
// records/thread, 5 independent loads per record batched (rec NT, parent x2,
// SPECULATIVE best x2) — R8 showed per-thread MLP is the limiter (VALUBusy
// 0.5%, HBM 0.9%). Speculative best read is safe: within a round bestC is
// monotone decreasing (atomicMin only), so a stale read can only cause a
// redundant atomic, never a missed bid. Record stream is non-temporal so it
// doesn't evict L2-resident parent/best. best[] ping-pongs; idle-buffer
// reset is a coalesced stream in choose (REQUIRED: stale winning key whose
// edge went internal would block future bids for that root => livelock).
// Endpoint pair (a,b) packed as u64 (a=low, b=high — little-endian) for NT
// stores; uint2 is not a valid nontemporal-builtin operand on clang/gfx950.
#define V_NODES 100000
#define MAX_ROUNDS 17   // components at least halve per active round; 2^17 > 1e5
#define TB 256
#define RPT 4           // records per scan thread

struct alignas(16) Rec { unsigned long long k; unsigned int a, b; };

__device__ __forceinline__ unsigned long long pack_ab(unsigned int a, unsigned int b) {
    return (unsigned long long)a | ((unsigned long long)b << 32);
}

// key = (~monotone_f32(score) << 32) | edge_id — min-key == best edge
// (largest score, ties -> smallest index, matching stable argsort(-scores)).
__device__ __forceinline__ unsigned long long make_key(float sv, float uv, int id) {
    float sp = 1.0f / (1.0f + expf(-sv));                 // sigmoid, f32 chain
    float g  = -logf(-logf(uv + 1e-9f) + 1e-9f);          // gumbel, f32 chain
    unsigned int b = __float_as_uint(sp + g);
    unsigned int m = (b & 0x80000000u) ? ~b : (b | 0x80000000u);
    return ((unsigned long long)(~m) << 32) | (unsigned int)id;
}

__device__ __forceinline__ int find_root(const int* __restrict__ parent, int v) {
    int p = parent[v];
    int pp = parent[p];
    while (p != pp) { p = pp; pp = parent[p]; }
    return p;
}

__global__ void k_init(int* __restrict__ parent, unsigned long long* __restrict__ bestA,
                       unsigned long long* __restrict__ bestB, int* __restrict__ flags) {
    int v = blockIdx.x * blockDim.x + threadIdx.x;
    if (v < MAX_ROUNDS) flags[v] = 0;
    if (v >= V_NODES) return;
    parent[v] = v;
    bestA[v] = ~0ULL;
    bestB[v] = ~0ULL;
}

// Round 0: endpoints ARE roots. Compute keys once, zero out[], build records,
// bid into bestA. Self-loops are born dead (a==b).
__global__ void k_scan0(const float* __restrict__ s, const float* __restrict__ u,
                        const int* __restrict__ src, const int* __restrict__ dst,
                        float* __restrict__ out, unsigned long long* __restrict__ best,
                        Rec* __restrict__ recs, int* __restrict__ flags, int E) {
    int e = blockIdx.x * blockDim.x + threadIdx.x;
    if (e >= E) return;
    unsigned int a = src[e], b = dst[e];
    unsigned long long k = make_key(s[e], u[e], e);
    __builtin_nontemporal_store(k, &recs[e].k);
    __builtin_nontemporal_store(pack_ab(a, b), (unsigned long long*)&recs[e].a);
    out[e] = 0.0f;                           // harness poisons d_out each call
    if (a != b) {
        if (k < __hip_atomic_load(&best[a], __ATOMIC_RELAXED, __HIP_MEMORY_SCOPE_AGENT))
            atomicMin(&best[a], k);
        if (k < __hip_atomic_load(&best[b], __ATOMIC_RELAXED, __HIP_MEMORY_SCOPE_AGENT))
            atomicMin(&best[b], k);
    }
    if (e == 0) flags[0] = 1;
}

// Rounds >=1. RPT records per thread; 5 independent loads per record issued
// before any dependent work. Record endpoints are previous-round roots =>
// chases are 0-1 extra hops and the speculative best value is usually exact.
__global__ void k_scan(const int* __restrict__ parent,
                       unsigned long long* __restrict__ bestC,
                       Rec* __restrict__ recs, int* __restrict__ flags,
                       int r, int E) {
    __shared__ int sflag;
    if (flags[r - 1] == 0) return;           // converged: launch-cost only
    if (threadIdx.x == 0) sflag = 0;
    __syncthreads();
    int base = (blockIdx.x * blockDim.x + threadIdx.x) * RPT;
    bool cross = false;

    unsigned long long kk[RPT], ab[RPT];
    int pa[RPT], pb[RPT];
    unsigned long long sba[RPT], sbb[RPT];
    bool live[RPT];
    #pragma unroll
    for (int j = 0; j < RPT; ++j) {          // batched record loads (NT stream)
        int i = base + j;
        if (i < E) {
            kk[j] = __builtin_nontemporal_load(&recs[i].k);
            ab[j] = __builtin_nontemporal_load((const unsigned long long*)&recs[i].a);
        } else ab[j] = 0;
        live[j] = ((unsigned int)ab[j] != (unsigned int)(ab[j] >> 32));
    }
    #pragma unroll
    for (int j = 0; j < RPT; ++j)            // batched first-hop gathers
        if (live[j]) {
            pa[j] = parent[(unsigned int)ab[j]];
            pb[j] = parent[(unsigned int)(ab[j] >> 32)];
        }
    #pragma unroll
    for (int j = 0; j < RPT; ++j)            // batched SPECULATIVE best reads
        if (live[j]) {
            sba[j] = __hip_atomic_load(&bestC[(unsigned int)ab[j]], __ATOMIC_RELAXED, __HIP_MEMORY_SCOPE_AGENT);
            sbb[j] = __hip_atomic_load(&bestC[(unsigned int)(ab[j] >> 32)], __ATOMIC_RELAXED, __HIP_MEMORY_SCOPE_AGENT);
        }
    #pragma unroll
    for (int j = 0; j < RPT; ++j) {
        if (!live[j]) continue;
        int i = base + j;
        unsigned int a0 = (unsigned int)ab[j], b0 = (unsigned int)(ab[j] >> 32);
        int ra = pa[j], rb = pb[j];
        int p = parent[ra]; while (ra != p) { ra = p; p = parent[ra]; }
        p = parent[rb];     while (rb != p) { rb = p; p = parent[rb]; }
        if (ra == rb) {
            __builtin_nontemporal_store(pack_ab(ra, ra),
                (unsigned long long*)&recs[i].a);                    // dead
        } else {
            cross = true;
            if ((unsigned)ra != a0 || (unsigned)rb != b0)
                __builtin_nontemporal_store(pack_ab(ra, rb),
                    (unsigned long long*)&recs[i].a);                // shortcut
            unsigned long long k = kk[j];
            // spec value is exact when endpoint was already the root; else
            // re-read. Monotonicity of atomicMin makes the skip test safe.
            unsigned long long va = ((unsigned)ra == a0) ? sba[j]
                : __hip_atomic_load(&bestC[ra], __ATOMIC_RELAXED, __HIP_MEMORY_SCOPE_AGENT);
            unsigned long long vb = ((unsigned)rb == b0) ? sbb[j]
                : __hip_atomic_load(&bestC[rb], __ATOMIC_RELAXED, __HIP_MEMORY_SCOPE_AGENT);
            if (k < va) atomicMin(&bestC[ra], k);
            if (k < vb) atomicMin(&bestC[rb], k);
        }
    }
    if (cross) sflag = 1;                    // LDS race benign (same value)
    __syncthreads();
    if (threadIdx.x == 0 && sflag) flags[r] = 1;
}

// V-domain winner/hook + coalesced reset of the NEXT round's best buffer
// (bestN = B_{r+1} = B_{r-1}: dead between choose r-1 and scan r+1, so this
// is the safe slot). v's winning record is unique (key embeds edge id): mark
// the edge (cut property => in MSF) and hook v into the partner's tree.
// Mutual pair broken by root id; hook chains follow strictly decreasing keys
// => acyclic. Stale best entries resolve to a redundant out-write.
__global__ void k_choose(const int* __restrict__ src, const int* __restrict__ dst,
                         int* __restrict__ parent,
                         const unsigned long long* __restrict__ bestC,
                         unsigned long long* __restrict__ bestN,
                         float* __restrict__ out, const int* __restrict__ flags,
                         int r) {
    if (flags[r] == 0) return;               // no bids => no future rounds
    int v = blockIdx.x * blockDim.x + threadIdx.x;
    if (v >= V_NODES) return;
    __builtin_nontemporal_store(~0ULL, &bestN[v]);   // coalesced stream reset
    unsigned long long k = bestC[v];
    if (k == ~0ULL) return;
    int id = (int)(unsigned int)(k & 0xffffffffu);
    int a0 = src[id], b0 = dst[id];
    int ru = find_root(parent, a0);
    int rv = find_root(parent, b0);
    if (ru != a0) parent[a0] = ru;           // compress original-vertex chains
    if (rv != b0) parent[b0] = rv;
    int other = (ru == v) ? rv : ru;
    out[id] = 1.0f;
    if (bestC[other] != k || v > other) {    // not mutual, or id tie-break won
        if (other != v) parent[v] = other;
    }
}

extern "C" void kernel_launch(void* const* d_in, const int* in_sizes, int n_in,
                              void* d_out, int out_size, void* d_ws, size_t ws_size,
                              hipStream_t stream) {
    const float* s  = (const float*)d_in[0];
    const float* u  = (const float*)d_in[1];
    const int*   ei = (const int*)d_in[2];
    const int E = in_sizes[0];
    const int* src = ei;
    const int* dst = ei + E;
    float* out = (float*)d_out;

    char* ws = (char*)d_ws;                                      // 16B-aligned
    Rec* recs = (Rec*)ws;                                        // E*16 = 6.4 MB
    unsigned long long* bestA = (unsigned long long*)(recs + E); // V*8
    unsigned long long* bestB = bestA + V_NODES;                 // V*8
    int* parent = (int*)(bestB + V_NODES);                       // V*4
    int* flags  = parent + V_NODES;                              // MAX_ROUNDS*4
    // total ~8.4 MB

    const int gE  = (E + TB - 1) / TB;
    const int gE4 = (E + TB * RPT - 1) / (TB * RPT);
    const int gV  = (V_NODES + TB - 1) / TB;

    k_init<<<gV, TB, 0, stream>>>(parent, bestA, bestB, flags);
    k_scan0<<<gE, TB, 0, stream>>>(s, u, src, dst, out, bestA, recs, flags, E);
    // choose 0: bestC=A, reset bestN=B (already clean — harmless)
    k_choose<<<gV, TB, 0, stream>>>(src, dst, parent, bestA, bestB, out, flags, 0);

    for (int r = 1; r < MAX_ROUNDS; ++r) {
        unsigned long long* bc = (r & 1) ? bestB : bestA;   // bid target B_r
        unsigned long long* bn = (r & 1) ? bestA : bestB;   // reset B_{r+1}
        k_scan<<<gE4, TB, 0, stream>>>(parent, bc, recs, flags, r, E);
        k_choose<<<gV, TB, 0, stream>>>(src, dst, parent, bc, bn, out, flags, r);
    }
}

// Round 11
// 2789.424 us; speedup vs baseline: 1.0318x; 1.0318x over previous
//
#include <hip/hip_runtime.h>
#include <stdint.h>

// Borůvka maximum-spanning-forest == Kruskal acceptance set under the strict
// total order (score desc, edge-index asc). Multi-launch (kernel boundary =
// cheap barrier; coop grid.sync measured 2.3x slower, R2). Two kernels per
// round: scan (bid) and choose (winner mark + hook + next-buffer reset).
//
// Structure (R11 = R8 + speculative best reads, NO non-temporal):
// - No compaction (records die too slowly on random graphs — R5).
// - Records updated IN PLACE (dead => a==b), PLAIN loads/stores: the 6.4MB
//   record buffer is L2-resident between rounds (R8 FETCH=3.3MB/scan proves
//   it); R10's nontemporal hints bypassed L2 and cost 11x — never NT a
//   buffer that is re-read next round.
// - Scan: 4 records/thread, 5 independent loads per record batched (rec,
//   parent x2, SPECULATIVE best x2) — R8 showed per-thread MLP is the
//   limiter. Speculative best is safe: within a round bestC only decreases
//   (atomicMin), so a stale value can only cause a redundant atomic, never
//   a missed bid; it is exact when the endpoint is already the root (common
//   case after in-place root rewriting).
// - best[] ping-pongs; idle-buffer reset is a coalesced stream in choose
//   (REQUIRED: a stale winning key whose edge went internal would block all
//   future bids for that root => livelock).
#define V_NODES 100000
#define MAX_ROUNDS 17   // components at least halve per active round; 2^17 > 1e5
#define TB 256
#define RPT 4           // records per scan thread

struct alignas(16) Rec { unsigned long long k; unsigned int a, b; };

// key = (~monotone_f32(score) << 32) | edge_id — min-key == best edge
// (largest score, ties -> smallest index, matching stable argsort(-scores)).
__device__ __forceinline__ unsigned long long make_key(float sv, float uv, int id) {
    float sp = 1.0f / (1.0f + expf(-sv));                 // sigmoid, f32 chain
    float g  = -logf(-logf(uv + 1e-9f) + 1e-9f);          // gumbel, f32 chain
    unsigned int b = __float_as_uint(sp + g);
    unsigned int m = (b & 0x80000000u) ? ~b : (b | 0x80000000u);
    return ((unsigned long long)(~m) << 32) | (unsigned int)id;
}

__device__ __forceinline__ int find_root(const int* __restrict__ parent, int v) {
    int p = parent[v];
    int pp = parent[p];
    while (p != pp) { p = pp; pp = parent[p]; }
    return p;
}

__global__ void k_init(int* __restrict__ parent, unsigned long long* __restrict__ bestA,
                       unsigned long long* __restrict__ bestB, int* __restrict__ flags) {
    int v = blockIdx.x * blockDim.x + threadIdx.x;
    if (v < MAX_ROUNDS) flags[v] = 0;
    if (v >= V_NODES) return;
    parent[v] = v;
    bestA[v] = ~0ULL;
    bestB[v] = ~0ULL;
}

// Round 0: endpoints ARE roots. Compute keys once, zero out[], build records,
// bid into bestA. Self-loops are born dead (a==b).
__global__ void k_scan0(const float* __restrict__ s, const float* __restrict__ u,
                        const int* __restrict__ src, const int* __restrict__ dst,
                        float* __restrict__ out, unsigned long long* __restrict__ best,
                        Rec* __restrict__ recs, int* __restrict__ flags, int E) {
    int e = blockIdx.x * blockDim.x + threadIdx.x;
    if (e >= E) return;
    unsigned int a = src[e], b = dst[e];
    Rec r;
    r.k = make_key(s[e], u[e], e);
    r.a = a; r.b = b;
    recs[e] = r;
    out[e] = 0.0f;                           // harness poisons d_out each call
    if (a != b) {
        if (r.k < __hip_atomic_load(&best[a], __ATOMIC_RELAXED, __HIP_MEMORY_SCOPE_AGENT))
            atomicMin(&best[a], r.k);
        if (r.k < __hip_atomic_load(&best[b], __ATOMIC_RELAXED, __HIP_MEMORY_SCOPE_AGENT))
            atomicMin(&best[b], r.k);
    }
    if (e == 0) flags[0] = 1;
}

// Rounds >=1. RPT records per thread; 5 independent loads per record issued
// before any dependent work. Record endpoints are previous-round roots =>
// chases are 0-1 extra hops and the speculative best value is usually exact.
__global__ void k_scan(const int* __restrict__ parent,
                       unsigned long long* __restrict__ bestC,
                       Rec* __restrict__ recs, int* __restrict__ flags,
                       int r, int E) {
    __shared__ int sflag;
    if (flags[r - 1] == 0) return;           // converged: launch-cost only
    if (threadIdx.x == 0) sflag = 0;
    __syncthreads();
    int base = (blockIdx.x * blockDim.x + threadIdx.x) * RPT;
    bool cross = false;

    Rec rec[RPT];
    int pa[RPT], pb[RPT];
    unsigned long long sba[RPT], sbb[RPT];
    bool live[RPT];
    #pragma unroll
    for (int j = 0; j < RPT; ++j) {          // batched record loads
        int i = base + j;
        if (i < E) rec[j] = recs[i];
        else { rec[j].a = 0; rec[j].b = 0; }
        live[j] = (rec[j].a != rec[j].b);
    }
    #pragma unroll
    for (int j = 0; j < RPT; ++j)            // batched first-hop gathers
        if (live[j]) { pa[j] = parent[rec[j].a]; pb[j] = parent[rec[j].b]; }
    #pragma unroll
    for (int j = 0; j < RPT; ++j)            // batched SPECULATIVE best reads
        if (live[j]) {
            sba[j] = __hip_atomic_load(&bestC[rec[j].a], __ATOMIC_RELAXED, __HIP_MEMORY_SCOPE_AGENT);
            sbb[j] = __hip_atomic_load(&bestC[rec[j].b], __ATOMIC_RELAXED, __HIP_MEMORY_SCOPE_AGENT);
        }
    #pragma unroll
    for (int j = 0; j < RPT; ++j) {
        if (!live[j]) continue;
        int i = base + j;
        int ra = pa[j], rb = pb[j];
        int p = parent[ra]; while (ra != p) { ra = p; p = parent[ra]; }
        p = parent[rb];     while (rb != p) { rb = p; p = parent[rb]; }
        if (ra == rb) {
            *(uint2*)&recs[i].a = make_uint2((unsigned)ra, (unsigned)ra);  // dead
        } else {
            cross = true;
            if ((unsigned)ra != rec[j].a || (unsigned)rb != rec[j].b)
                *(uint2*)&recs[i].a = make_uint2((unsigned)ra, (unsigned)rb);
            unsigned long long k = rec[j].k;
            // spec value is exact when endpoint was already the root; else
            // re-read. atomicMin monotonicity makes the skip test safe.
            unsigned long long va = ((unsigned)ra == rec[j].a) ? sba[j]
                : __hip_atomic_load(&bestC[ra], __ATOMIC_RELAXED, __HIP_MEMORY_SCOPE_AGENT);
            unsigned long long vb = ((unsigned)rb == rec[j].b) ? sbb[j]
                : __hip_atomic_load(&bestC[rb], __ATOMIC_RELAXED, __HIP_MEMORY_SCOPE_AGENT);
            if (k < va) atomicMin(&bestC[ra], k);
            if (k < vb) atomicMin(&bestC[rb], k);
        }
    }
    if (cross) sflag = 1;                    // LDS race benign (same value)
    __syncthreads();
    if (threadIdx.x == 0 && sflag) flags[r] = 1;
}

// V-domain winner/hook + coalesced reset of the NEXT round's best buffer
// (bestN = B_{r+1} = B_{r-1}: dead between choose r-1 and scan r+1, so this
// is the safe slot). v's winning record is unique (key embeds edge id): mark
// the edge (cut property => in MSF) and hook v into the partner's tree.
// Mutual pair broken by root id; hook chains follow strictly decreasing keys
// => acyclic. Stale best entries resolve to a redundant out-write.
__global__ void k_choose(const int* __restrict__ src, const int* __restrict__ dst,
                         int* __restrict__ parent,
                         const unsigned long long* __restrict__ bestC,
                         unsigned long long* __restrict__ bestN,
                         float* __restrict__ out, const int* __restrict__ flags,
                         int r) {
    if (flags[r] == 0) return;               // no bids => no future rounds
    int v = blockIdx.x * blockDim.x + threadIdx.x;
    if (v >= V_NODES) return;
    bestN[v] = ~0ULL;                        // coalesced stream reset
    unsigned long long k = bestC[v];
    if (k == ~0ULL) return;
    int id = (int)(unsigned int)(k & 0xffffffffu);
    int a0 = src[id], b0 = dst[id];
    int ru = find_root(parent, a0);
    int rv = find_root(parent, b0);
    if (ru != a0) parent[a0] = ru;           // compress original-vertex chains
    if (rv != b0) parent[b0] = rv;
    int other = (ru == v) ? rv : ru;
    out[id] = 1.0f;
    if (bestC[other] != k || v > other) {    // not mutual, or id tie-break won
        if (other != v) parent[v] = other;
    }
}

extern "C" void kernel_launch(void* const* d_in, const int* in_sizes, int n_in,
                              void* d_out, int out_size, void* d_ws, size_t ws_size,
                              hipStream_t stream) {
    const float* s  = (const float*)d_in[0];
    const float* u  = (const float*)d_in[1];
    const int*   ei = (const int*)d_in[2];
    const int E = in_sizes[0];
    const int* src = ei;
    const int* dst = ei + E;
    float* out = (float*)d_out;

    char* ws = (char*)d_ws;                                      // 16B-aligned
    Rec* recs = (Rec*)ws;                                        // E*16 = 6.4 MB
    unsigned long long* bestA = (unsigned long long*)(recs + E); // V*8
    unsigned long long* bestB = bestA + V_NODES;                 // V*8
    int* parent = (int*)(bestB + V_NODES);                       // V*4
    int* flags  = parent + V_NODES;                              // MAX_ROUNDS*4
    // total ~8.4 MB

    const int gE  = (E + TB - 1) / TB;
    const int gE4 = (E + TB * RPT - 1) / (TB * RPT);
    const int gV  = (V_NODES + TB - 1) / TB;

    k_init<<<gV, TB, 0, stream>>>(parent, bestA, bestB, flags);
    k_scan0<<<gE, TB, 0, stream>>>(s, u, src, dst, out, bestA, recs, flags, E);
    // choose 0: bestC=A, reset bestN=B (already clean — harmless)
    k_choose<<<gV, TB, 0, stream>>>(src, dst, parent, bestA, bestB, out, flags, 0);

    for (int r = 1; r < MAX_ROUNDS; ++r) {
        unsigned long long* bc = (r & 1) ? bestB : bestA;   // bid target B_r
        unsigned long long* bn = (r & 1) ? bestA : bestB;   // reset B_{r+1}
        k_scan<<<gE4, TB, 0, stream>>>(parent, bc, recs, flags, r, E);
        k_choose<<<gV, TB, 0, stream>>>(src, dst, parent, bc, bn, out, flags, r);
    }
}

// Round 12
// 472.402 us; speedup vs baseline: 6.0925x; 5.9048x over previous
//
#include <hip/hip_runtime.h>
#include <stdint.h>

// Borůvka maximum-spanning-forest == Kruskal acceptance set under the strict
// total order (score desc, edge-index asc). Multi-launch (kernel boundary =
// cheap barrier; coop grid.sync measured 2.3x slower, R2). Two kernels per
// round: scan (bid) and choose (winner mark + hook + next-buffer reset).
//
// Structure (R12 = R8 + plain-load checks):
// - No compaction (records die too slowly on random graphs — R5).
// - Records updated IN PLACE (dead => a==b), PLAIN loads/stores: record
//   buffer is L2-resident between rounds (R8 FETCH=3.3MB/scan). R10's
//   non-temporal hints bypassed L2: 5x regression. Never NT a re-read buffer.
// - Scan: 4 records/thread, batched independent loads (rec, parent x2) —
//   per-thread MLP is the limiter (R7->R8 gave 1.8x).
// - DEVICE-SCOPE ATOMIC LOADS ARE THE SCARCE RESOURCE (R9-R11: doubling
//   them cost 5x; they bypass the non-coherent per-XCD L2s and serialize at
//   the coherence point). The check-before-atomic therefore uses a PLAIN
//   load: best[] only decreases within a round (atomicMin), so a stale
//   (too-high) value only causes a redundant atomicMin, never a missed bid;
//   64-bit loads don't tear. atomicMin is the only remaining coherent op.
// - best[] ping-pongs; idle-buffer reset is a coalesced stream in choose
//   (REQUIRED: a stale winning key whose edge went internal would block all
//   future bids for that root => livelock).
#define V_NODES 100000
#define MAX_ROUNDS 17   // components at least halve per active round; 2^17 > 1e5
#define TB 256
#define RPT 4           // records per scan thread

struct alignas(16) Rec { unsigned long long k; unsigned int a, b; };

// key = (~monotone_f32(score) << 32) | edge_id — min-key == best edge
// (largest score, ties -> smallest index, matching stable argsort(-scores)).
__device__ __forceinline__ unsigned long long make_key(float sv, float uv, int id) {
    float sp = 1.0f / (1.0f + expf(-sv));                 // sigmoid, f32 chain
    float g  = -logf(-logf(uv + 1e-9f) + 1e-9f);          // gumbel, f32 chain
    unsigned int b = __float_as_uint(sp + g);
    unsigned int m = (b & 0x80000000u) ? ~b : (b | 0x80000000u);
    return ((unsigned long long)(~m) << 32) | (unsigned int)id;
}

__device__ __forceinline__ int find_root(const int* __restrict__ parent, int v) {
    int p = parent[v];
    int pp = parent[p];
    while (p != pp) { p = pp; pp = parent[p]; }
    return p;
}

__global__ void k_init(int* __restrict__ parent, unsigned long long* __restrict__ bestA,
                       unsigned long long* __restrict__ bestB, int* __restrict__ flags) {
    int v = blockIdx.x * blockDim.x + threadIdx.x;
    if (v < MAX_ROUNDS) flags[v] = 0;
    if (v >= V_NODES) return;
    parent[v] = v;
    bestA[v] = ~0ULL;
    bestB[v] = ~0ULL;
}

// Round 0: endpoints ARE roots. Compute keys once, zero out[], build records,
// bid into bestA. Self-loops are born dead (a==b).
__global__ void k_scan0(const float* __restrict__ s, const float* __restrict__ u,
                        const int* __restrict__ src, const int* __restrict__ dst,
                        float* __restrict__ out, unsigned long long* __restrict__ best,
                        Rec* __restrict__ recs, int* __restrict__ flags, int E) {
    int e = blockIdx.x * blockDim.x + threadIdx.x;
    if (e >= E) return;
    unsigned int a = src[e], b = dst[e];
    Rec r;
    r.k = make_key(s[e], u[e], e);
    r.a = a; r.b = b;
    recs[e] = r;
    out[e] = 0.0f;                           // harness poisons d_out each call
    if (a != b) {
        if (r.k < best[a]) atomicMin(&best[a], r.k);   // plain-load check (safe)
        if (r.k < best[b]) atomicMin(&best[b], r.k);
    }
    if (e == 0) flags[0] = 1;
}

// Rounds >=1. RPT records per thread; record loads then first-hop parent
// gathers issued as independent batches (MLP). Record endpoints are
// previous-round roots => chases are 0-1 extra hops.
__global__ void k_scan(const int* __restrict__ parent,
                       unsigned long long* __restrict__ bestC,
                       Rec* __restrict__ recs, int* __restrict__ flags,
                       int r, int E) {
    __shared__ int sflag;
    if (flags[r - 1] == 0) return;           // converged: launch-cost only
    if (threadIdx.x == 0) sflag = 0;
    __syncthreads();
    int base = (blockIdx.x * blockDim.x + threadIdx.x) * RPT;
    bool cross = false;

    Rec rec[RPT];
    int pa[RPT], pb[RPT];
    bool live[RPT];
    #pragma unroll
    for (int j = 0; j < RPT; ++j) {          // batched record loads
        int i = base + j;
        if (i < E) rec[j] = recs[i];
        else { rec[j].a = 0; rec[j].b = 0; }
        live[j] = (rec[j].a != rec[j].b);
    }
    #pragma unroll
    for (int j = 0; j < RPT; ++j)            // batched first-hop gathers
        if (live[j]) { pa[j] = parent[rec[j].a]; pb[j] = parent[rec[j].b]; }
    #pragma unroll
    for (int j = 0; j < RPT; ++j) {
        if (!live[j]) continue;
        int i = base + j;
        int ra = pa[j], rb = pb[j];
        int p = parent[ra]; while (ra != p) { ra = p; p = parent[ra]; }
        p = parent[rb];     while (rb != p) { rb = p; p = parent[rb]; }
        if (ra == rb) {
            *(uint2*)&recs[i].a = make_uint2((unsigned)ra, (unsigned)ra);  // dead
        } else {
            cross = true;
            if ((unsigned)ra != rec[j].a || (unsigned)rb != rec[j].b)
                *(uint2*)&recs[i].a = make_uint2((unsigned)ra, (unsigned)rb);
            unsigned long long k = rec[j].k;
            // PLAIN-load check: best only decreases within a round, so a
            // stale value only causes a redundant atomicMin (never a miss).
            if (k < bestC[ra]) atomicMin(&bestC[ra], k);
            if (k < bestC[rb]) atomicMin(&bestC[rb], k);
        }
    }
    if (cross) sflag = 1;                    // LDS race benign (same value)
    __syncthreads();
    if (threadIdx.x == 0 && sflag) flags[r] = 1;
}

// V-domain winner/hook + coalesced reset of the NEXT round's best buffer
// (bestN = B_{r+1} = B_{r-1}: dead between choose r-1 and scan r+1, so this
// is the safe slot). v's winning record is unique (key embeds edge id): mark
// the edge (cut property => in MSF) and hook v into the partner's tree.
// Mutual pair broken by root id; hook chains follow strictly decreasing keys
// => acyclic. Stale best entries resolve to a redundant out-write.
__global__ void k_choose(const int* __restrict__ src, const int* __restrict__ dst,
                         int* __restrict__ parent,
                         const unsigned long long* __restrict__ bestC,
                         unsigned long long* __restrict__ bestN,
                         float* __restrict__ out, const int* __restrict__ flags,
                         int r) {
    if (flags[r] == 0) return;               // no bids => no future rounds
    int v = blockIdx.x * blockDim.x + threadIdx.x;
    if (v >= V_NODES) return;
    bestN[v] = ~0ULL;                        // coalesced stream reset
    unsigned long long k = bestC[v];
    if (k == ~0ULL) return;
    int id = (int)(unsigned int)(k & 0xffffffffu);
    int a0 = src[id], b0 = dst[id];
    int ru = find_root(parent, a0);
    int rv = find_root(parent, b0);
    if (ru != a0) parent[a0] = ru;           // compress original-vertex chains
    if (rv != b0) parent[b0] = rv;
    int other = (ru == v) ? rv : ru;
    out[id] = 1.0f;
    if (bestC[other] != k || v > other) {    // not mutual, or id tie-break won
        if (other != v) parent[v] = other;
    }
}

extern "C" void kernel_launch(void* const* d_in, const int* in_sizes, int n_in,
                              void* d_out, int out_size, void* d_ws, size_t ws_size,
                              hipStream_t stream) {
    const float* s  = (const float*)d_in[0];
    const float* u  = (const float*)d_in[1];
    const int*   ei = (const int*)d_in[2];
    const int E = in_sizes[0];
    const int* src = ei;
    const int* dst = ei + E;
    float* out = (float*)d_out;

    char* ws = (char*)d_ws;                                      // 16B-aligned
    Rec* recs = (Rec*)ws;                                        // E*16 = 6.4 MB
    unsigned long long* bestA = (unsigned long long*)(recs + E); // V*8
    unsigned long long* bestB = bestA + V_NODES;                 // V*8
    int* parent = (int*)(bestB + V_NODES);                       // V*4
    int* flags  = parent + V_NODES;                              // MAX_ROUNDS*4
    // total ~8.4 MB

    const int gE  = (E + TB - 1) / TB;
    const int gE4 = (E + TB * RPT - 1) / (TB * RPT);
    const int gV  = (V_NODES + TB - 1) / TB;

    k_init<<<gV, TB, 0, stream>>>(parent, bestA, bestB, flags);
    k_scan0<<<gE, TB, 0, stream>>>(s, u, src, dst, out, bestA, recs, flags, E);
    // choose 0: bestC=A, reset bestN=B (already clean — harmless)
    k_choose<<<gV, TB, 0, stream>>>(src, dst, parent, bestA, bestB, out, flags, 0);

    for (int r = 1; r < MAX_ROUNDS; ++r) {
        unsigned long long* bc = (r & 1) ? bestB : bestA;   // bid target B_r
        unsigned long long* bn = (r & 1) ? bestA : bestB;   // reset B_{r+1}
        k_scan<<<gE4, TB, 0, stream>>>(parent, bc, recs, flags, r, E);
        k_choose<<<gV, TB, 0, stream>>>(src, dst, parent, bc, bn, out, flags, r);
    }
}

// Round 13
// 359.833 us; speedup vs baseline: 7.9985x; 1.3128x over previous
//
#include <hip/hip_runtime.h>
#include <stdint.h>

// Borůvka maximum-spanning-forest == Kruskal acceptance set under the strict
// total order (score desc, edge-index asc). Multi-launch (kernel boundary =
// cheap barrier; coop grid.sync measured 2.3x slower, R2). Two kernels per
// round: scan (bid) and choose (winner mark + hook + next-buffer reset).
//
// Structure (R13 = R12 + LDS bid aggregation):
// - No compaction: with random endpoints P(edge internal at K comps) ~ 1/K,
//   so ~all 400k edges stay live until K is tiny (R5 measured).
// - Records updated IN PLACE (dead => a==b), PLAIN loads/stores (R10: NT
//   hints bypass L2, 5x regression).
// - Scan: 4 records/thread, batched independent loads (MLP limiter, R7->R8).
// - Device-scope atomic LOADS are the scarce resource (R11: 5x). Checks use
//   PLAIN loads (safe: best only decreases; stale-high => redundant atomic).
// - NEW: per-block LDS hash (root -> min key) aggregates bids before global
//   atomicMin. Late rounds K<=2048: 2048 bids/block collapse to <=K global
//   atomics — the coherence-point serialization (~800k atomics onto K lines)
//   was the late-round floor. Hash collisions fall back to the R12 path;
//   min is associative so the result is identical.
// - best[] ping-pongs; idle-buffer reset is a coalesced stream in choose
//   (REQUIRED: stale winning key of an internal edge would livelock).
#define V_NODES 100000
#define MAX_ROUNDS 17   // components at least halve per active round; 2^17 > 1e5
#define TB 256
#define RPT 4           // records per scan thread
#define TBL 2048        // LDS bid-table slots (power of 2)

struct alignas(16) Rec { unsigned long long k; unsigned int a, b; };

// key = (~monotone_f32(score) << 32) | edge_id — min-key == best edge
// (largest score, ties -> smallest index, matching stable argsort(-scores)).
__device__ __forceinline__ unsigned long long make_key(float sv, float uv, int id) {
    float sp = 1.0f / (1.0f + expf(-sv));                 // sigmoid, f32 chain
    float g  = -logf(-logf(uv + 1e-9f) + 1e-9f);          // gumbel, f32 chain
    unsigned int b = __float_as_uint(sp + g);
    unsigned int m = (b & 0x80000000u) ? ~b : (b | 0x80000000u);
    return ((unsigned long long)(~m) << 32) | (unsigned int)id;
}

__device__ __forceinline__ int find_root(const int* __restrict__ parent, int v) {
    int p = parent[v];
    int pp = parent[p];
    while (p != pp) { p = pp; pp = parent[p]; }
    return p;
}

__global__ void k_init(int* __restrict__ parent, unsigned long long* __restrict__ bestA,
                       unsigned long long* __restrict__ bestB, int* __restrict__ flags) {
    int v = blockIdx.x * blockDim.x + threadIdx.x;
    if (v < MAX_ROUNDS) flags[v] = 0;
    if (v >= V_NODES) return;
    parent[v] = v;
    bestA[v] = ~0ULL;
    bestB[v] = ~0ULL;
}

// Round 0: endpoints ARE roots (K=100k => negligible atomic contention, no
// LDS table needed). Compute keys once, zero out[], build records, bid.
__global__ void k_scan0(const float* __restrict__ s, const float* __restrict__ u,
                        const int* __restrict__ src, const int* __restrict__ dst,
                        float* __restrict__ out, unsigned long long* __restrict__ best,
                        Rec* __restrict__ recs, int* __restrict__ flags, int E) {
    int e = blockIdx.x * blockDim.x + threadIdx.x;
    if (e >= E) return;
    unsigned int a = src[e], b = dst[e];
    Rec r;
    r.k = make_key(s[e], u[e], e);
    r.a = a; r.b = b;
    recs[e] = r;
    out[e] = 0.0f;                           // harness poisons d_out each call
    if (a != b) {
        if (r.k < best[a]) atomicMin(&best[a], r.k);   // plain-load check (safe)
        if (r.k < best[b]) atomicMin(&best[b], r.k);
    }
    if (e == 0) flags[0] = 1;
}

// Rounds >=1. RPT records per thread; batched independent loads; bids go
// through the per-block LDS table, flushed once at the end.
__global__ void k_scan(const int* __restrict__ parent,
                       unsigned long long* __restrict__ bestC,
                       Rec* __restrict__ recs, int* __restrict__ flags,
                       int r, int E) {
    __shared__ int sflag;
    __shared__ unsigned int tag[TBL];
    __shared__ unsigned long long tkey[TBL];
    if (flags[r - 1] == 0) return;           // converged: launch-cost only
    for (int t = threadIdx.x; t < TBL; t += TB) { tag[t] = 0xFFFFFFFFu; tkey[t] = ~0ULL; }
    if (threadIdx.x == 0) sflag = 0;
    __syncthreads();

    int base = (blockIdx.x * blockDim.x + threadIdx.x) * RPT;
    bool cross = false;

    Rec rec[RPT];
    int pa[RPT], pb[RPT];
    bool live[RPT];
    #pragma unroll
    for (int j = 0; j < RPT; ++j) {          // batched record loads
        int i = base + j;
        if (i < E) rec[j] = recs[i];
        else { rec[j].a = 0; rec[j].b = 0; }
        live[j] = (rec[j].a != rec[j].b);
    }
    #pragma unroll
    for (int j = 0; j < RPT; ++j)            // batched first-hop gathers
        if (live[j]) { pa[j] = parent[rec[j].a]; pb[j] = parent[rec[j].b]; }

    auto bid = [&](unsigned int root, unsigned long long k) {
        unsigned int slot = root & (TBL - 1);
        unsigned int prev = atomicCAS(&tag[slot], 0xFFFFFFFFu, root);
        if (prev == 0xFFFFFFFFu || prev == root) {
            atomicMin(&tkey[slot], k);       // LDS atomic: cheap, no coherence
        } else {                             // collision: R12 fallback path
            if (k < bestC[root]) atomicMin(&bestC[root], k);
        }
    };

    #pragma unroll
    for (int j = 0; j < RPT; ++j) {
        if (!live[j]) continue;
        int i = base + j;
        int ra = pa[j], rb = pb[j];
        int p = parent[ra]; while (ra != p) { ra = p; p = parent[ra]; }
        p = parent[rb];     while (rb != p) { rb = p; p = parent[rb]; }
        if (ra == rb) {
            *(uint2*)&recs[i].a = make_uint2((unsigned)ra, (unsigned)ra);  // dead
        } else {
            cross = true;
            if ((unsigned)ra != rec[j].a || (unsigned)rb != rec[j].b)
                *(uint2*)&recs[i].a = make_uint2((unsigned)ra, (unsigned)rb);
            bid((unsigned)ra, rec[j].k);
            bid((unsigned)rb, rec[j].k);
        }
    }
    if (cross) sflag = 1;                    // LDS race benign (same value)
    __syncthreads();

    // flush: one global atomic per distinct root per block
    for (int t = threadIdx.x; t < TBL; t += TB) {
        unsigned int rt = tag[t];
        if (rt != 0xFFFFFFFFu) {
            unsigned long long k = tkey[t];
            if (k < bestC[rt]) atomicMin(&bestC[rt], k);   // plain-load check
        }
    }
    if (threadIdx.x == 0 && sflag) flags[r] = 1;
}

// V-domain winner/hook + coalesced reset of the NEXT round's best buffer
// (bestN = B_{r+1} = B_{r-1}: dead between choose r-1 and scan r+1, so this
// is the safe slot). v's winning record is unique (key embeds edge id): mark
// the edge (cut property => in MSF) and hook v into the partner's tree.
// Mutual pair broken by root id; hook chains follow strictly decreasing keys
// => acyclic. Stale best entries resolve to a redundant out-write.
__global__ void k_choose(const int* __restrict__ src, const int* __restrict__ dst,
                         int* __restrict__ parent,
                         const unsigned long long* __restrict__ bestC,
                         unsigned long long* __restrict__ bestN,
                         float* __restrict__ out, const int* __restrict__ flags,
                         int r) {
    if (flags[r] == 0) return;               // no bids => no future rounds
    int v = blockIdx.x * blockDim.x + threadIdx.x;
    if (v >= V_NODES) return;
    bestN[v] = ~0ULL;                        // coalesced stream reset
    unsigned long long k = bestC[v];
    if (k == ~0ULL) return;
    int id = (int)(unsigned int)(k & 0xffffffffu);
    int a0 = src[id], b0 = dst[id];
    int ru = find_root(parent, a0);
    int rv = find_root(parent, b0);
    if (ru != a0) parent[a0] = ru;           // compress original-vertex chains
    if (rv != b0) parent[b0] = rv;
    int other = (ru == v) ? rv : ru;
    out[id] = 1.0f;
    if (bestC[other] != k || v > other) {    // not mutual, or id tie-break won
        if (other != v) parent[v] = other;
    }
}

extern "C" void kernel_launch(void* const* d_in, const int* in_sizes, int n_in,
                              void* d_out, int out_size, void* d_ws, size_t ws_size,
                              hipStream_t stream) {
    const float* s  = (const float*)d_in[0];
    const float* u  = (const float*)d_in[1];
    const int*   ei = (const int*)d_in[2];
    const int E = in_sizes[0];
    const int* src = ei;
    const int* dst = ei + E;
    float* out = (float*)d_out;

    char* ws = (char*)d_ws;                                      // 16B-aligned
    Rec* recs = (Rec*)ws;                                        // E*16 = 6.4 MB
    unsigned long long* bestA = (unsigned long long*)(recs + E); // V*8
    unsigned long long* bestB = bestA + V_NODES;                 // V*8
    int* parent = (int*)(bestB + V_NODES);                       // V*4
    int* flags  = parent + V_NODES;                              // MAX_ROUNDS*4
    // total ~8.4 MB

    const int gE  = (E + TB - 1) / TB;
    const int gE4 = (E + TB * RPT - 1) / (TB * RPT);
    const int gV  = (V_NODES + TB - 1) / TB;

    k_init<<<gV, TB, 0, stream>>>(parent, bestA, bestB, flags);
    k_scan0<<<gE, TB, 0, stream>>>(s, u, src, dst, out, bestA, recs, flags, E);
    // choose 0: bestC=A, reset bestN=B (already clean — harmless)
    k_choose<<<gV, TB, 0, stream>>>(src, dst, parent, bestA, bestB, out, flags, 0);

    for (int r = 1; r < MAX_ROUNDS; ++r) {
        unsigned long long* bc = (r & 1) ? bestB : bestA;   // bid target B_r
        unsigned long long* bn = (r & 1) ? bestA : bestB;   // reset B_{r+1}
        k_scan<<<gE4, TB, 0, stream>>>(parent, bc, recs, flags, r, E);
        k_choose<<<gV, TB, 0, stream>>>(src, dst, parent, bc, bn, out, flags, r);
    }
}